// Round 6
// baseline (1685.344 us; speedup 1.0000x reference)
//
#include <hip/hip_runtime.h>
#include <stdint.h>

#define INV_T 10.0f
#define SHIFT_ 460.0f
#define MROWS 8192
#define DDIM 1024
#define CHUNK 1024

typedef __attribute__((ext_vector_type(8))) short bf16x8;
typedef __attribute__((ext_vector_type(4))) float f32x4;

__device__ __forceinline__ float bf2f(unsigned short u) {
  return __uint_as_float(((unsigned int)u) << 16);
}
__device__ __forceinline__ unsigned short f2bf(float f) {
  unsigned int u = __float_as_uint(f);
  return (unsigned short)((u + 0x7FFFu + ((u >> 16) & 1u)) >> 16);
}
__device__ __forceinline__ void gl2lds16(const unsigned short* g, unsigned short* l) {
  __builtin_amdgcn_global_load_lds((const __attribute__((address_space(1))) void*)g,
                                   (__attribute__((address_space(3))) void*)l, 16, 0, 0);
}

// ---------------- prep: fp32 -> bf16 cast + row sum-of-squares ----------------
__global__ void prep_kernel(const float* __restrict__ gen, const float* __restrict__ pos,
                            unsigned short* __restrict__ gen_h, unsigned short* __restrict__ pos_h,
                            float* __restrict__ gn2, float* __restrict__ pn2) {
  int b = blockIdx.x;
  const float* src; unsigned short* dst; float* n2; int row;
  if (b < MROWS) { src = gen; dst = gen_h; n2 = gn2; row = b; }
  else           { src = pos; dst = pos_h; n2 = pn2; row = b - MROWS; }
  int t = threadIdx.x;
  float4 v = ((const float4*)(src + (size_t)row * DDIM))[t];
  float ss = v.x * v.x + v.y * v.y + v.z * v.z + v.w * v.w;
  ushort4 o;
  o.x = f2bf(v.x); o.y = f2bf(v.y); o.z = f2bf(v.z); o.w = f2bf(v.w);
  ((ushort4*)(dst + (size_t)row * DDIM))[t] = o;
#pragma unroll
  for (int m = 1; m < 64; m <<= 1) ss += __shfl_xor(ss, m);
  __shared__ float red[4];
  if ((t & 63) == 0) red[t >> 6] = ss;
  __syncthreads();
  if (t == 0) n2[row] = red[0] + red[1] + red[2] + red[3];
}

// ---------------- transpose: fp32 [8192][1024] -> bf16 [1024][8192] ----------------
__global__ void transpose_kernel(const float* __restrict__ gen, const float* __restrict__ pos,
                                 unsigned short* __restrict__ genT, unsigned short* __restrict__ posT) {
  __shared__ float tile[64][65];
  int b = blockIdx.x;
  const float* src; unsigned short* dst;
  if (b < 2048) { src = gen; dst = genT; }
  else          { src = pos; dst = posT; b -= 2048; }
  int tj = b >> 4, td = b & 15;
  int t = threadIdx.x;
#pragma unroll
  for (int it = 0; it < 16; ++it) {
    int idx = it * 256 + t;
    int r = idx >> 6, c = idx & 63;
    tile[r][c] = src[(size_t)(tj * 64 + r) * DDIM + td * 64 + c];
  }
  __syncthreads();
#pragma unroll
  for (int it = 0; it < 16; ++it) {
    int idx = it * 256 + t;
    int d = idx >> 6, j = idx & 63;
    dst[(size_t)(td * 64 + d) * MROWS + tj * 64 + j] = f2bf(tile[j][d]);
  }
}

// ---------------- BT-GEMM, 256x128 tile, XOR-swizzled LDS, dual-stream via blockIdx.z ----------------
// z=0: attraction stream, z=1: repulsion stream (masked diag).
// EPI 0: score epilogue -> P bf16 chunk + row-sum atomics into lsum
// EPI 1: PV epilogue -> O bf16 (first ? write : accumulate)
// NOTE: __launch_bounds__(256,1): acc needs 128 VGPR; (256,2) empirically caps at 128 -> spills.
template <int EPI>
__launch_bounds__(256, 1)
__global__ void gemm_bt(const unsigned short* __restrict__ A0, const unsigned short* __restrict__ A1,
                        long lda,
                        const unsigned short* __restrict__ B0, const unsigned short* __restrict__ B1,
                        long ldb, int ksteps,
                        unsigned short* __restrict__ P0, unsigned short* __restrict__ P1,
                        int pld, int j0,
                        const float* __restrict__ qn2,
                        const float* __restrict__ kn2a, const float* __restrict__ kn2b,
                        float* __restrict__ lsum0, float* __restrict__ lsum1,
                        unsigned short* __restrict__ O0, unsigned short* __restrict__ O1,
                        int first) {
  __shared__ __align__(16) unsigned short Al[256 * 64];  // 32 KB
  __shared__ __align__(16) unsigned short Bl[128 * 64];  // 16 KB
  const int z = blockIdx.z;
  const unsigned short* A = z ? A1 : A0;
  const unsigned short* B = z ? B1 : B0;
  const int t = threadIdx.x;
  const int w = t >> 6, lane = t & 63, l15 = lane & 15, quad = lane >> 4;
  const int wm = w >> 1, wn = w & 1;          // wave: 128 rows (wm) x 64 cols (wn)
  const long m0 = (long)blockIdx.x * 256;
  const long n0 = (long)blockIdx.y * 128;
  const int trow = t >> 3;                       // 0..31
  const int tcol = (((t & 7) ^ (trow & 7)) * 8); // XOR-swizzled global 16B-unit

  f32x4 acc[8][4];
#pragma unroll
  for (int i = 0; i < 8; ++i)
#pragma unroll
    for (int j = 0; j < 4; ++j) acc[i][j] = (f32x4){0.f, 0.f, 0.f, 0.f};

  const unsigned short* Ab = A + (m0 + trow) * lda + tcol;
  const unsigned short* Bb = B + (n0 + trow) * ldb + tcol;
  unsigned short* Alw = Al + t * 8;  // lane-linear LDS dest (byte = t*16)
  unsigned short* Blw = Bl + t * 8;
  const int ue = (quad ^ (l15 & 7)) * 8;  // swizzled read unit (elems)

  for (int ks = 0; ks < ksteps; ++ks) {
    const long ko = (long)ks * 64;
#pragma unroll
    for (int i = 0; i < 8; ++i) gl2lds16(Ab + (long)i * 32 * lda + ko, Alw + i * 2048);
#pragma unroll
    for (int i = 0; i < 4; ++i) gl2lds16(Bb + (long)i * 32 * ldb + ko, Blw + i * 2048);
    __syncthreads();
#pragma unroll
    for (int kk = 0; kk < 2; ++kk) {
      const int uo = ue ^ (kk * 32);
      bf16x8 af[8], bfr[4];
#pragma unroll
      for (int mi = 0; mi < 8; ++mi)
        af[mi] = *(const bf16x8*)(Al + (wm * 128 + mi * 16 + l15) * 64 + uo);
#pragma unroll
      for (int ni = 0; ni < 4; ++ni)
        bfr[ni] = *(const bf16x8*)(Bl + (wn * 64 + ni * 16 + l15) * 64 + uo);
#pragma unroll
      for (int mi = 0; mi < 8; ++mi)
#pragma unroll
        for (int ni = 0; ni < 4; ++ni)
          acc[mi][ni] = __builtin_amdgcn_mfma_f32_16x16x32_bf16(af[mi], bfr[ni], acc[mi][ni], 0, 0, 0);
    }
    __syncthreads();
  }

  if (EPI == 0) {
    unsigned short* Pout = z ? P1 : P0;
    const float* kn2 = z ? kn2b : kn2a;
    float* lsum = z ? lsum1 : lsum0;
#pragma unroll
    for (int mi = 0; mi < 8; ++mi) {
      float rs[4] = {0.f, 0.f, 0.f, 0.f};
#pragma unroll
      for (int ni = 0; ni < 4; ++ni) {
        int c = (int)n0 + wn * 64 + ni * 16 + l15;  // chunk-local col
        float kn = kn2[j0 + c];
#pragma unroll
        for (int reg = 0; reg < 4; ++reg) {
          long r = m0 + wm * 128 + mi * 16 + quad * 4 + reg;  // C-layout: row = quad*4+reg
          float v = acc[mi][ni][reg];
          float d2 = qn2[r] + kn - 2.0f * v;
          float p = __expf(SHIFT_ - INV_T * sqrtf(fmaxf(d2, 0.0f)));
          if (z && (int)r == (j0 + c)) p = 0.0f;
          rs[reg] += p;
          Pout[r * (long)pld + c] = f2bf(p);
        }
      }
#pragma unroll
      for (int reg = 0; reg < 4; ++reg) {
        float v = rs[reg];
        v += __shfl_xor(v, 1); v += __shfl_xor(v, 2);
        v += __shfl_xor(v, 4); v += __shfl_xor(v, 8);
        if (l15 == 0) atomicAdd(&lsum[m0 + wm * 128 + mi * 16 + quad * 4 + reg], v);
      }
    }
  } else {
    unsigned short* Oh = z ? O1 : O0;
#pragma unroll
    for (int mi = 0; mi < 8; ++mi)
#pragma unroll
      for (int ni = 0; ni < 4; ++ni) {
        long c = n0 + wn * 64 + ni * 16 + l15;
#pragma unroll
        for (int reg = 0; reg < 4; ++reg) {
          long r = m0 + wm * 128 + mi * 16 + quad * 4 + reg;
          long off = r * DDIM + c;
          float v = acc[mi][ni][reg];
          Oh[off] = f2bf(first ? v : (bf2f(Oh[off]) + v));
        }
      }
  }
}

// ---------------- merged epilogue: all four stats in one pass; 4 atomics/block ----------------
__global__ void epi_kernel(const unsigned short* __restrict__ OA, const unsigned short* __restrict__ OR_,
                           const float* __restrict__ lsumA, const float* __restrict__ lsumR,
                           const float* __restrict__ genf, float* __restrict__ gs) {
  __shared__ float wsL[4], wsD[4], wsA[4], wsR[4];
  const int t = threadIdx.x;
  const int w = t >> 6;
  const int lane = t & 63;
  float accL = 0.f, accD = 0.f, accA = 0.f, accR = 0.f;

  for (int i = 0; i < 8; ++i) {
    const int row = blockIdx.x * 32 + w * 8 + i;
    const float invlA = 1.0f / lsumA[row];
    const float invlR = 1.0f / lsumR[row];
    float ssA = 0.f, ssR = 0.f, ssD = 0.f;
#pragma unroll
    for (int u = 0; u < 4; ++u) {
      const long off = (long)row * DDIM + u * 256 + lane * 4;
      float4 g = *(const float4*)(genf + off);
      ushort4 oa = *(const ushort4*)(OA + off);
      ushort4 orr = *(const ushort4*)(OR_ + off);
      float g4[4] = {g.x, g.y, g.z, g.w};
      float a4[4] = {bf2f(oa.x), bf2f(oa.y), bf2f(oa.z), bf2f(oa.w)};
      float r4[4] = {bf2f(orr.x), bf2f(orr.y), bf2f(orr.z), bf2f(orr.w)};
#pragma unroll
      for (int e = 0; e < 4; ++e) {
        float a_ = a4[e] * invlA - g4[e];
        float r_ = r4[e] * invlR - g4[e];
        float d_ = a_ - r_;
        ssA += a_ * a_; ssR += r_ * r_; ssD += d_ * d_;
      }
    }
#pragma unroll
    for (int m = 1; m < 64; m <<= 1) {
      ssA += __shfl_xor(ssA, m);
      ssR += __shfl_xor(ssR, m);
      ssD += __shfl_xor(ssD, m);
    }
    accA += sqrtf(ssA); accR += sqrtf(ssR); accD += sqrtf(ssD); accL += ssD;
  }
  if (lane == 0) { wsL[w] = accL; wsD[w] = accD; wsA[w] = accA; wsR[w] = accR; }
  __syncthreads();
  if (t == 0) {
    atomicAdd(&gs[0], wsL[0] + wsL[1] + wsL[2] + wsL[3]);
    atomicAdd(&gs[1], wsD[0] + wsD[1] + wsD[2] + wsD[3]);
    atomicAdd(&gs[2], wsA[0] + wsA[1] + wsA[2] + wsA[3]);
    atomicAdd(&gs[3], wsR[0] + wsR[1] + wsR[2] + wsR[3]);
  }
}

__global__ void finalize_kernel(const float* __restrict__ gs, float* __restrict__ out) {
  int t = threadIdx.x;
  if (t == 0) out[0] = gs[0] / (8192.0f * 1024.0f);
  if (t == 1) out[1] = gs[1] / 8192.0f;
  if (t == 2) out[2] = gs[2] / 8192.0f;
  if (t == 3) out[3] = gs[3] / 8192.0f;
}

extern "C" void kernel_launch(void* const* d_in, const int* in_sizes, int n_in,
                              void* d_out, int out_size, void* d_ws, size_t ws_size,
                              hipStream_t stream) {
  const float* gen = (const float*)d_in[0];
  const float* pos = (const float*)d_in[1];
  char* ws = (char*)d_ws;
  const size_t MB = (size_t)1 << 20;
  unsigned short* gen_h = (unsigned short*)(ws + 0 * MB);    // 16 MB
  unsigned short* pos_h = (unsigned short*)(ws + 16 * MB);   // 16 MB
  unsigned short* genT  = (unsigned short*)(ws + 32 * MB);   // 16 MB
  unsigned short* posT  = (unsigned short*)(ws + 48 * MB);   // 16 MB
  unsigned short* Pa    = (unsigned short*)(ws + 64 * MB);   // 16 MB  (attr P chunk)
  unsigned short* Pr    = (unsigned short*)(ws + 80 * MB);   // 16 MB  (rep P chunk)
  unsigned short* OhA   = (unsigned short*)(ws + 96 * MB);   // 16 MB  (attr O, bf16)
  unsigned short* OhR   = (unsigned short*)(ws + 112 * MB);  // 16 MB  (rep O, bf16)
  float* gn2   = (float*)(ws + 128 * MB);                    // 32 KB
  float* pn2   = (float*)(ws + 128 * MB + 32768);            // 32 KB
  float* lsumA = (float*)(ws + 128 * MB + 65536);            // 32 KB
  float* lsumR = (float*)(ws + 128 * MB + 98304);            // 32 KB
  float* gs    = (float*)(ws + 128 * MB + 131072);           // 16 B

  hipMemsetAsync(gs, 0, 4 * sizeof(float), stream);
  hipMemsetAsync(lsumA, 0, 2 * MROWS * sizeof(float), stream);  // lsumA + lsumR contiguous
  prep_kernel<<<dim3(16384), dim3(256), 0, stream>>>(gen, pos, gen_h, pos_h, gn2, pn2);
  transpose_kernel<<<dim3(4096), dim3(256), 0, stream>>>(gen, pos, genT, posT);

  const int nchunks = MROWS / CHUNK;
  for (int c = 0; c < nchunks; ++c) {
    const int j0 = c * CHUNK;
    // PassA: S-chunk for both streams; A = gen_h for both, B = pos_h / gen_h rows [j0, j0+CHUNK)
    gemm_bt<0><<<dim3(MROWS / 256, CHUNK / 128, 2), dim3(256), 0, stream>>>(
        gen_h, gen_h, DDIM,
        pos_h + (long)j0 * DDIM, gen_h + (long)j0 * DDIM, DDIM, DDIM / 64,
        Pa, Pr, CHUNK, j0, gn2, pn2, gn2, lsumA, lsumR, nullptr, nullptr, 0);
    // PassB: O += P-chunk @ V; A = P chunks, B = transposed V slabs
    gemm_bt<1><<<dim3(MROWS / 256, DDIM / 128, 2), dim3(256), 0, stream>>>(
        Pa, Pr, CHUNK,
        posT + j0, genT + j0, MROWS, CHUNK / 64,
        nullptr, nullptr, 0, 0, nullptr, nullptr, nullptr, nullptr, nullptr,
        OhA, OhR, c == 0);
  }

  epi_kernel<<<dim3(256), dim3(256), 0, stream>>>(OhA, OhR, lsumA, lsumR, gen, gs);
  finalize_kernel<<<dim3(1), dim3(64), 0, stream>>>(gs, (float*)d_out);
}

// Round 8
// 959.424 us; speedup vs baseline: 1.7566x; 1.7566x over previous
//
#include <hip/hip_runtime.h>
#include <stdint.h>

#define INV_T 10.0f
#define SHIFT_ 460.0f
#define MROWS 8192
#define DDIM 1024
#define CHUNK 1024

typedef __attribute__((ext_vector_type(8))) short bf16x8;
typedef __attribute__((ext_vector_type(4))) float f32x4;

__device__ __forceinline__ float bf2f(unsigned short u) {
  return __uint_as_float(((unsigned int)u) << 16);
}
__device__ __forceinline__ unsigned short f2bf(float f) {
  unsigned int u = __float_as_uint(f);
  return (unsigned short)((u + 0x7FFFu + ((u >> 16) & 1u)) >> 16);
}
__device__ __forceinline__ void gl2lds16(const unsigned short* g, unsigned short* l) {
  __builtin_amdgcn_global_load_lds((const __attribute__((address_space(1))) void*)g,
                                   (__attribute__((address_space(3))) void*)l, 16, 0, 0);
}

// ---------------- prep: fp32 -> bf16 cast + row sum-of-squares ----------------
__global__ void prep_kernel(const float* __restrict__ gen, const float* __restrict__ pos,
                            unsigned short* __restrict__ gen_h, unsigned short* __restrict__ pos_h,
                            float* __restrict__ gn2, float* __restrict__ pn2) {
  int b = blockIdx.x;
  const float* src; unsigned short* dst; float* n2; int row;
  if (b < MROWS) { src = gen; dst = gen_h; n2 = gn2; row = b; }
  else           { src = pos; dst = pos_h; n2 = pn2; row = b - MROWS; }
  int t = threadIdx.x;
  float4 v = ((const float4*)(src + (size_t)row * DDIM))[t];
  float ss = v.x * v.x + v.y * v.y + v.z * v.z + v.w * v.w;
  ushort4 o;
  o.x = f2bf(v.x); o.y = f2bf(v.y); o.z = f2bf(v.z); o.w = f2bf(v.w);
  ((ushort4*)(dst + (size_t)row * DDIM))[t] = o;
#pragma unroll
  for (int m = 1; m < 64; m <<= 1) ss += __shfl_xor(ss, m);
  __shared__ float red[4];
  if ((t & 63) == 0) red[t >> 6] = ss;
  __syncthreads();
  if (t == 0) n2[row] = red[0] + red[1] + red[2] + red[3];
}

// ---------------- transpose: fp32 [8192][1024] -> bf16 [1024][8192] ----------------
__global__ void transpose_kernel(const float* __restrict__ gen, const float* __restrict__ pos,
                                 unsigned short* __restrict__ genT, unsigned short* __restrict__ posT) {
  __shared__ float tile[64][65];
  int b = blockIdx.x;
  const float* src; unsigned short* dst;
  if (b < 2048) { src = gen; dst = genT; }
  else          { src = pos; dst = posT; b -= 2048; }
  int tj = b >> 4, td = b & 15;
  int t = threadIdx.x;
#pragma unroll
  for (int it = 0; it < 16; ++it) {
    int idx = it * 256 + t;
    int r = idx >> 6, c = idx & 63;
    tile[r][c] = src[(size_t)(tj * 64 + r) * DDIM + td * 64 + c];
  }
  __syncthreads();
#pragma unroll
  for (int it = 0; it < 16; ++it) {
    int idx = it * 256 + t;
    int d = idx >> 6, j = idx & 63;
    dst[(size_t)(td * 64 + d) * MROWS + tj * 64 + j] = f2bf(tile[j][d]);
  }
}

// ---------------- BT-GEMM, 256x128 tile, XOR-swizzled LDS, dual-stream via blockIdx.z ----------------
// z=0: attraction stream, z=1: repulsion stream (masked diag).
// EPI 0: score epilogue -> P bf16 chunk + row-sum atomics into lsum
// EPI 1: PV epilogue -> O bf16 (first ? write : accumulate)
// __launch_bounds__(256,2): unified reg cap 256/wave = 128 acc (AGPR) + <=128 arch.
// (R6 post-mortem: (256,1) let arch hit 160 -> 288 unified -> 1 wave/SIMD collapse.)
template <int EPI>
__launch_bounds__(256, 2)
__global__ void gemm_bt(const unsigned short* __restrict__ A0, const unsigned short* __restrict__ A1,
                        long lda,
                        const unsigned short* __restrict__ B0, const unsigned short* __restrict__ B1,
                        long ldb, int ksteps,
                        unsigned short* __restrict__ P0, unsigned short* __restrict__ P1,
                        int pld, int j0,
                        const float* __restrict__ qn2,
                        const float* __restrict__ kn2a, const float* __restrict__ kn2b,
                        float* __restrict__ lsum0, float* __restrict__ lsum1,
                        unsigned short* __restrict__ O0, unsigned short* __restrict__ O1,
                        int first) {
  __shared__ __align__(16) unsigned short Al[256 * 64];  // 32 KB
  __shared__ __align__(16) unsigned short Bl[128 * 64];  // 16 KB
  const int z = blockIdx.z;
  const unsigned short* A = z ? A1 : A0;
  const unsigned short* B = z ? B1 : B0;
  const int t = threadIdx.x;
  const int w = t >> 6, lane = t & 63, l15 = lane & 15, quad = lane >> 4;
  const int wm = w >> 1, wn = w & 1;          // wave: 128 rows (wm) x 64 cols (wn)
  const long m0 = (long)blockIdx.x * 256;
  const long n0 = (long)blockIdx.y * 128;
  const int trow = t >> 3;                       // 0..31
  const int tcol = (((t & 7) ^ (trow & 7)) * 8); // XOR-swizzled global 16B-unit

  f32x4 acc[8][4];
#pragma unroll
  for (int i = 0; i < 8; ++i)
#pragma unroll
    for (int j = 0; j < 4; ++j) acc[i][j] = (f32x4){0.f, 0.f, 0.f, 0.f};

  const unsigned short* Ab = A + (m0 + trow) * lda + tcol;
  const unsigned short* Bb = B + (n0 + trow) * ldb + tcol;
  unsigned short* Alw = Al + t * 8;  // lane-linear LDS dest (byte = t*16)
  unsigned short* Blw = Bl + t * 8;
  const int ue = (quad ^ (l15 & 7)) * 8;  // swizzled read unit (elems)

  for (int ks = 0; ks < ksteps; ++ks) {
    const long ko = (long)ks * 64;
#pragma unroll
    for (int i = 0; i < 8; ++i) gl2lds16(Ab + (long)i * 32 * lda + ko, Alw + i * 2048);
#pragma unroll
    for (int i = 0; i < 4; ++i) gl2lds16(Bb + (long)i * 32 * ldb + ko, Blw + i * 2048);
    __syncthreads();
#pragma unroll
    for (int kk = 0; kk < 2; ++kk) {
      const int uo = ue ^ (kk * 32);
      bf16x8 af[8], bfr[4];
#pragma unroll
      for (int mi = 0; mi < 8; ++mi)
        af[mi] = *(const bf16x8*)(Al + (wm * 128 + mi * 16 + l15) * 64 + uo);
#pragma unroll
      for (int ni = 0; ni < 4; ++ni)
        bfr[ni] = *(const bf16x8*)(Bl + (wn * 64 + ni * 16 + l15) * 64 + uo);
#pragma unroll
      for (int mi = 0; mi < 8; ++mi)
#pragma unroll
        for (int ni = 0; ni < 4; ++ni)
          acc[mi][ni] = __builtin_amdgcn_mfma_f32_16x16x32_bf16(af[mi], bfr[ni], acc[mi][ni], 0, 0, 0);
    }
    __syncthreads();
  }

  if (EPI == 0) {
    unsigned short* Pout = z ? P1 : P0;
    const float* kn2 = z ? kn2b : kn2a;
    float* lsum = z ? lsum1 : lsum0;
#pragma unroll
    for (int mi = 0; mi < 8; ++mi) {
      float rs[4] = {0.f, 0.f, 0.f, 0.f};
#pragma unroll
      for (int ni = 0; ni < 4; ++ni) {
        int c = (int)n0 + wn * 64 + ni * 16 + l15;  // chunk-local col
        float kn = kn2[j0 + c];
#pragma unroll
        for (int reg = 0; reg < 4; ++reg) {
          long r = m0 + wm * 128 + mi * 16 + quad * 4 + reg;  // C-layout: row = quad*4+reg
          float v = acc[mi][ni][reg];
          float d2 = qn2[r] + kn - 2.0f * v;
          float p = __expf(SHIFT_ - INV_T * __builtin_amdgcn_sqrtf(fmaxf(d2, 0.0f)));
          if (z && (int)r == (j0 + c)) p = 0.0f;
          rs[reg] += p;
          Pout[r * (long)pld + c] = f2bf(p);
        }
      }
#pragma unroll
      for (int reg = 0; reg < 4; ++reg) {
        float v = rs[reg];
        v += __shfl_xor(v, 1); v += __shfl_xor(v, 2);
        v += __shfl_xor(v, 4); v += __shfl_xor(v, 8);
        if (l15 == 0) atomicAdd(&lsum[m0 + wm * 128 + mi * 16 + quad * 4 + reg], v);
      }
    }
  } else {
    unsigned short* Oh = z ? O1 : O0;
#pragma unroll
    for (int mi = 0; mi < 8; ++mi)
#pragma unroll
      for (int ni = 0; ni < 4; ++ni) {
        long c = n0 + wn * 64 + ni * 16 + l15;
#pragma unroll
        for (int reg = 0; reg < 4; ++reg) {
          long r = m0 + wm * 128 + mi * 16 + quad * 4 + reg;
          long off = r * DDIM + c;
          float v = acc[mi][ni][reg];
          Oh[off] = f2bf(first ? v : (bf2f(Oh[off]) + v));
        }
      }
  }
}

// ---------------- merged epilogue: all four stats in one pass; 4 atomics/block ----------------
__global__ void epi_kernel(const unsigned short* __restrict__ OA, const unsigned short* __restrict__ OR_,
                           const float* __restrict__ lsumA, const float* __restrict__ lsumR,
                           const float* __restrict__ genf, float* __restrict__ gs) {
  __shared__ float wsL[4], wsD[4], wsA[4], wsR[4];
  const int t = threadIdx.x;
  const int w = t >> 6;
  const int lane = t & 63;
  float accL = 0.f, accD = 0.f, accA = 0.f, accR = 0.f;

  for (int i = 0; i < 8; ++i) {
    const int row = blockIdx.x * 32 + w * 8 + i;
    const float invlA = 1.0f / lsumA[row];
    const float invlR = 1.0f / lsumR[row];
    float ssA = 0.f, ssR = 0.f, ssD = 0.f;
#pragma unroll
    for (int u = 0; u < 4; ++u) {
      const long off = (long)row * DDIM + u * 256 + lane * 4;
      float4 g = *(const float4*)(genf + off);
      ushort4 oa = *(const ushort4*)(OA + off);
      ushort4 orr = *(const ushort4*)(OR_ + off);
      float g4[4] = {g.x, g.y, g.z, g.w};
      float a4[4] = {bf2f(oa.x), bf2f(oa.y), bf2f(oa.z), bf2f(oa.w)};
      float r4[4] = {bf2f(orr.x), bf2f(orr.y), bf2f(orr.z), bf2f(orr.w)};
#pragma unroll
      for (int e = 0; e < 4; ++e) {
        float a_ = a4[e] * invlA - g4[e];
        float r_ = r4[e] * invlR - g4[e];
        float d_ = a_ - r_;
        ssA += a_ * a_; ssR += r_ * r_; ssD += d_ * d_;
      }
    }
#pragma unroll
    for (int m = 1; m < 64; m <<= 1) {
      ssA += __shfl_xor(ssA, m);
      ssR += __shfl_xor(ssR, m);
      ssD += __shfl_xor(ssD, m);
    }
    accA += sqrtf(ssA); accR += sqrtf(ssR); accD += sqrtf(ssD); accL += ssD;
  }
  if (lane == 0) { wsL[w] = accL; wsD[w] = accD; wsA[w] = accA; wsR[w] = accR; }
  __syncthreads();
  if (t == 0) {
    atomicAdd(&gs[0], wsL[0] + wsL[1] + wsL[2] + wsL[3]);
    atomicAdd(&gs[1], wsD[0] + wsD[1] + wsD[2] + wsD[3]);
    atomicAdd(&gs[2], wsA[0] + wsA[1] + wsA[2] + wsA[3]);
    atomicAdd(&gs[3], wsR[0] + wsR[1] + wsR[2] + wsR[3]);
  }
}

__global__ void finalize_kernel(const float* __restrict__ gs, float* __restrict__ out) {
  int t = threadIdx.x;
  if (t == 0) out[0] = gs[0] / (8192.0f * 1024.0f);
  if (t == 1) out[1] = gs[1] / 8192.0f;
  if (t == 2) out[2] = gs[2] / 8192.0f;
  if (t == 3) out[3] = gs[3] / 8192.0f;
}

extern "C" void kernel_launch(void* const* d_in, const int* in_sizes, int n_in,
                              void* d_out, int out_size, void* d_ws, size_t ws_size,
                              hipStream_t stream) {
  const float* gen = (const float*)d_in[0];
  const float* pos = (const float*)d_in[1];
  char* ws = (char*)d_ws;
  const size_t MB = (size_t)1 << 20;
  unsigned short* gen_h = (unsigned short*)(ws + 0 * MB);    // 16 MB
  unsigned short* pos_h = (unsigned short*)(ws + 16 * MB);   // 16 MB
  unsigned short* genT  = (unsigned short*)(ws + 32 * MB);   // 16 MB
  unsigned short* posT  = (unsigned short*)(ws + 48 * MB);   // 16 MB
  unsigned short* Pa    = (unsigned short*)(ws + 64 * MB);   // 16 MB  (attr P chunk)
  unsigned short* Pr    = (unsigned short*)(ws + 80 * MB);   // 16 MB  (rep P chunk)
  unsigned short* OhA   = (unsigned short*)(ws + 96 * MB);   // 16 MB  (attr O, bf16)
  unsigned short* OhR   = (unsigned short*)(ws + 112 * MB);  // 16 MB  (rep O, bf16)
  float* gn2   = (float*)(ws + 128 * MB);                    // 32 KB
  float* pn2   = (float*)(ws + 128 * MB + 32768);            // 32 KB
  float* lsumA = (float*)(ws + 128 * MB + 65536);            // 32 KB
  float* lsumR = (float*)(ws + 128 * MB + 98304);            // 32 KB
  float* gs    = (float*)(ws + 128 * MB + 131072);           // 16 B

  hipMemsetAsync(gs, 0, 4 * sizeof(float), stream);
  hipMemsetAsync(lsumA, 0, 2 * MROWS * sizeof(float), stream);  // lsumA + lsumR contiguous
  prep_kernel<<<dim3(16384), dim3(256), 0, stream>>>(gen, pos, gen_h, pos_h, gn2, pn2);
  transpose_kernel<<<dim3(4096), dim3(256), 0, stream>>>(gen, pos, genT, posT);

  const int nchunks = MROWS / CHUNK;
  for (int c = 0; c < nchunks; ++c) {
    const int j0 = c * CHUNK;
    // PassA: S-chunk for both streams; A = gen_h for both, B = pos_h / gen_h rows [j0, j0+CHUNK)
    gemm_bt<0><<<dim3(MROWS / 256, CHUNK / 128, 2), dim3(256), 0, stream>>>(
        gen_h, gen_h, DDIM,
        pos_h + (long)j0 * DDIM, gen_h + (long)j0 * DDIM, DDIM, DDIM / 64,
        Pa, Pr, CHUNK, j0, gn2, pn2, gn2, lsumA, lsumR, nullptr, nullptr, 0);
    // PassB: O += P-chunk @ V; A = P chunks, B = transposed V slabs
    gemm_bt<1><<<dim3(MROWS / 256, DDIM / 128, 2), dim3(256), 0, stream>>>(
        Pa, Pr, CHUNK,
        posT + j0, genT + j0, MROWS, CHUNK / 64,
        nullptr, nullptr, 0, 0, nullptr, nullptr, nullptr, nullptr, nullptr,
        OhA, OhR, c == 0);
  }

  epi_kernel<<<dim3(256), dim3(256), 0, stream>>>(OhA, OhR, lsumA, lsumR, gen, gs);
  finalize_kernel<<<dim3(1), dim3(64), 0, stream>>>(gs, (float*)d_out);
}